// Round 4
// baseline (463.456 us; speedup 1.0000x reference)
//
#include <hip/hip_runtime.h>
#include <hip/hip_bf16.h>
#include <stdint.h>

#define B_ 2048
#define L_ 128
#define V_ 50000
#define D_ 128

typedef __attribute__((ext_vector_type(8))) short bf16x8;
typedef __attribute__((ext_vector_type(8))) unsigned short ushort8;
typedef __attribute__((ext_vector_type(4))) float f32x4;

__device__ inline unsigned short f2bf(float f) {
    union { float f; uint32_t u; } v; v.f = f;
    uint32_t u = v.u + 0x7FFFu + ((v.u >> 16) & 1u);   // RNE
    return (unsigned short)(u >> 16);
}
__device__ inline float bf2f(unsigned short h) {
    union { uint32_t u; float f; } v; v.u = ((uint32_t)h) << 16;
    return v.f;
}
__device__ inline float tanh_fast(float x) {
    float xc = fminf(fmaxf(x, -15.f), 15.f);
    float z = __expf(2.f * xc);
    return (z - 1.f) / (z + 1.f);
}

// ---------------- kernel 0: aT_bf16[n][d] = bf16(attn_a[d][n]) ----------------
__global__ __launch_bounds__(256) void k_prep(const float* __restrict__ a,
                                              unsigned short* __restrict__ aT) {
    int i = blockIdx.x * 256 + threadIdx.x;   // 16384 elems
    int d = i >> 7, n = i & 127;
    aT[n * 128 + d] = f2bf(a[d * 128 + n]);
}

// ---------------- kernel 0b: emb_bf[v][d] = bf16(emb[v][d]) ----------------
__global__ __launch_bounds__(256) void k_convE(const float* __restrict__ emb,
                                               unsigned short* __restrict__ emb_bf) {
    size_t i = ((size_t)blockIdx.x * 256 + threadIdx.x) * 8;  // 6,400,000 elems, grid exact
    float4 x0 = *(const float4*)(emb + i);
    float4 x1 = *(const float4*)(emb + i + 4);
    ushort8 v;
    v[0] = f2bf(x0.x); v[1] = f2bf(x0.y); v[2] = f2bf(x0.z); v[3] = f2bf(x0.w);
    v[4] = f2bf(x1.x); v[5] = f2bf(x1.y); v[6] = f2bf(x1.z); v[7] = f2bf(x1.w);
    *(ushort8*)(emb_bf + i) = v;
}

// ---------------- kernel 1: user_bf16[b][d] ----------------
// one block per b; 256 threads = 4 waves; aT fragments read straight from L1/L2
__global__ __launch_bounds__(256) void k_user(
    const int* __restrict__ ids, const int* __restrict__ msk,
    const float* __restrict__ emb, const unsigned short* __restrict__ emb_bf,
    const unsigned short* __restrict__ aT,
    const float* __restrict__ bvec, unsigned short* __restrict__ user_bf,
    int use_bf) {
    __shared__ __align__(16) unsigned short lh[128 * 128];  // h tile, swizzled (32KB)
    __shared__ float l_e[128];
    __shared__ float l_attn[128];
    __shared__ float l_p[256];

    int b = blockIdx.x;
    int t = threadIdx.x;

    // stage h = emb[ids[b,:]] -> bf16 LDS (XOR swizzle on ushort index: c ^ ((row&7)<<3))
    {
        int row = t >> 1, half = t & 1;
        int id = ids[b * L_ + row];
        if (use_bf) {
            const unsigned short* src = emb_bf + (size_t)id * D_ + half * 64;
#pragma unroll
            for (int q = 0; q < 8; ++q) {
                ushort8 v = *(const ushort8*)(src + q * 8);
                int c = half * 64 + q * 8;
                *(ushort8*)&lh[row * 128 + (c ^ ((row & 7) << 3))] = v;
            }
        } else {
            const float* src = emb + (size_t)id * D_ + half * 64;
#pragma unroll
            for (int q = 0; q < 8; ++q) {
                float4 x0 = *(const float4*)(src + q * 8);
                float4 x1 = *(const float4*)(src + q * 8 + 4);
                ushort8 v;
                v[0] = f2bf(x0.x); v[1] = f2bf(x0.y); v[2] = f2bf(x0.z); v[3] = f2bf(x0.w);
                v[4] = f2bf(x1.x); v[5] = f2bf(x1.y); v[6] = f2bf(x1.z); v[7] = f2bf(x1.w);
                int c = half * 64 + q * 8;
                *(ushort8*)&lh[row * 128 + (c ^ ((row & 7) << 3))] = v;
            }
        }
    }
    __syncthreads();

    int wave = t >> 6, lane = t & 63, lo = lane & 15, hi = lane >> 4;

    // t = h @ a  via mfma 16x16x32 (M=128 rows of h, N=128, K=128)
    f32x4 acc[2][8] = {};
#pragma unroll
    for (int kk = 0; kk < 4; ++kk) {
        int kc = kk * 32 + hi * 8;   // k element offset
        bf16x8 afr[2];
#pragma unroll
        for (int mi = 0; mi < 2; ++mi) {
            int row = wave * 32 + mi * 16 + lo;
            afr[mi] = *(const bf16x8*)&lh[row * 128 + (kc ^ ((row & 7) << 3))];
        }
#pragma unroll
        for (int nj = 0; nj < 8; ++nj) {
            int col = nj * 16 + lo;
            bf16x8 bfr = *(const bf16x8*)(aT + col * 128 + kc);   // L1-resident (32KB)
            acc[0][nj] = __builtin_amdgcn_mfma_f32_16x16x32_bf16(afr[0], bfr, acc[0][nj], 0, 0, 0);
            acc[1][nj] = __builtin_amdgcn_mfma_f32_16x16x32_bf16(afr[1], bfr, acc[1][nj], 0, 0, 0);
        }
    }

    // e[row] = sum_n tanh(t[row,n]) * bvec[n] ; C/D layout: col=lo, row=hi*4+reg
    float bv[8];
#pragma unroll
    for (int nj = 0; nj < 8; ++nj) bv[nj] = bvec[nj * 16 + lo];
#pragma unroll
    for (int mi = 0; mi < 2; ++mi) {
#pragma unroll
        for (int reg = 0; reg < 4; ++reg) {
            float p = 0.f;
#pragma unroll
            for (int nj = 0; nj < 8; ++nj) p += tanh_fast(acc[mi][nj][reg]) * bv[nj];
            p += __shfl_xor(p, 1); p += __shfl_xor(p, 2);
            p += __shfl_xor(p, 4); p += __shfl_xor(p, 8);
            int row = wave * 32 + mi * 16 + hi * 4 + reg;
            if (lo == 0) l_e[row] = p;
        }
    }
    __syncthreads();

    if (t < 128) {
        float e = l_e[t];
        float at = 0.f;
        if (msk[b * L_ + t]) at = 1.f / (1.f + __expf(-e));
        l_attn[t] = at;
    }
    __syncthreads();

    // user[d] = sum_l attn[l] * h[l][d]
    {
        int d = t & 127, half = t >> 7;
        float s = 0.f;
#pragma unroll 8
        for (int l = half * 64; l < half * 64 + 64; ++l)
            s += l_attn[l] * bf2f(lh[l * 128 + (d ^ ((l & 7) << 3))]);
        l_p[t] = s;
    }
    __syncthreads();
    if (t < 128) {
        float u = l_p[t] + l_p[t + 128];
        user_bf[b * 128 + t] = f2bf(u);
    }
}

// ---------------- kernel 2: logits = user_bf16 @ emb^T + bias ----------------
// grid (2, 391): each block stages one 128-col emb tile ONCE, loops 8 M-tiles.
// Plain float4 stores (round-2 best config).
__global__ __launch_bounds__(256) void k_logits(
    const unsigned short* __restrict__ user_bf, const float* __restrict__ emb,
    const unsigned short* __restrict__ emb_bf,
    const float* __restrict__ bias, float* __restrict__ out, int use_bf) {
    __shared__ __align__(16) unsigned short lb[128 * 128];  // emb tile [n][k] bf16 swizzled (32KB)

    int t = threadIdx.x;
    int m_base = blockIdx.x * 1024;          // 2 chunks x 8 tiles of 128
    int n0 = blockIdx.y * 128;

    // stage B tile: emb rows n0..n0+127 -> bf16 LDS (guard tail rows -> 0)
    {
        int r = t >> 1, half = t & 1;
        int n = n0 + r;
        if (n < V_) {
            if (use_bf) {
                const unsigned short* src = emb_bf + (size_t)n * D_ + half * 64;
#pragma unroll
                for (int q = 0; q < 8; ++q) {
                    ushort8 v = *(const ushort8*)(src + q * 8);
                    int c = half * 64 + q * 8;
                    *(ushort8*)&lb[r * 128 + (c ^ ((r & 7) << 3))] = v;
                }
            } else {
                const float* src = emb + (size_t)n * D_ + half * 64;
#pragma unroll
                for (int q = 0; q < 8; ++q) {
                    float4 x0 = *(const float4*)(src + q * 8);
                    float4 x1 = *(const float4*)(src + q * 8 + 4);
                    ushort8 v;
                    v[0] = f2bf(x0.x); v[1] = f2bf(x0.y); v[2] = f2bf(x0.z); v[3] = f2bf(x0.w);
                    v[4] = f2bf(x1.x); v[5] = f2bf(x1.y); v[6] = f2bf(x1.z); v[7] = f2bf(x1.w);
                    int c = half * 64 + q * 8;
                    *(ushort8*)&lb[r * 128 + (c ^ ((r & 7) << 3))] = v;
                }
            }
        } else {
            ushort8 z = {0, 0, 0, 0, 0, 0, 0, 0};
#pragma unroll
            for (int q = 0; q < 8; ++q) {
                int c = half * 64 + q * 8;
                *(ushort8*)&lb[r * 128 + (c ^ ((r & 7) << 3))] = z;
            }
        }
    }

    int wave = t >> 6, lane = t & 63, lo = lane & 15, hi = lane >> 4;

    // bias: n = n0 + nj*16 + hi*4 + reg ; amortized over all 8 m-tiles
    float4 bb[8];
#pragma unroll
    for (int nj = 0; nj < 8; ++nj) {
        int n = n0 + nj * 16 + hi * 4;
        if (n + 3 < V_) {
            bb[nj] = *(const float4*)(bias + n);
        } else {
            bb[nj].x = (n + 0 < V_) ? bias[n + 0] : 0.f;
            bb[nj].y = (n + 1 < V_) ? bias[n + 1] : 0.f;
            bb[nj].z = (n + 2 < V_) ? bias[n + 2] : 0.f;
            bb[nj].w = (n + 3 < V_) ? bias[n + 3] : 0.f;
        }
    }
    __syncthreads();

#pragma unroll 1
    for (int mt = 0; mt < 8; ++mt) {
        int m0 = m_base + mt * 128;

        // A (user) fragments from global: 512KB total, L2-resident
        bf16x8 afr[2][4];
#pragma unroll
        for (int mi = 0; mi < 2; ++mi) {
            const unsigned short* ap = user_bf + (size_t)(m0 + wave * 32 + mi * 16 + lo) * 128;
#pragma unroll
            for (int kk = 0; kk < 4; ++kk)
                afr[mi][kk] = *(const bf16x8*)(ap + kk * 32 + hi * 8);
        }

        f32x4 acc[2][8] = {};
#pragma unroll
        for (int kk = 0; kk < 4; ++kk) {
            int kc = kk * 32 + hi * 8;
#pragma unroll
            for (int nj = 0; nj < 8; ++nj) {
                int col = nj * 16 + lo;
                bf16x8 bfr = *(const bf16x8*)&lb[col * 128 + (kc ^ ((col & 7) << 3))];
                // swapped: D[emb_idx][user_idx] -> lane holds 4 consecutive vocab cols
                acc[0][nj] = __builtin_amdgcn_mfma_f32_16x16x32_bf16(bfr, afr[0][kk], acc[0][nj], 0, 0, 0);
                acc[1][nj] = __builtin_amdgcn_mfma_f32_16x16x32_bf16(bfr, afr[1][kk], acc[1][nj], 0, 0, 0);
            }
        }

        // epilogue: row b from lo, 4 consecutive n per lane -> float4 store
#pragma unroll
        for (int mi = 0; mi < 2; ++mi) {
            int b = m0 + wave * 32 + mi * 16 + lo;
#pragma unroll
            for (int nj = 0; nj < 8; ++nj) {
                int n = n0 + nj * 16 + hi * 4;
                float4 o;
                o.x = acc[mi][nj][0] + bb[nj].x;
                o.y = acc[mi][nj][1] + bb[nj].y;
                o.z = acc[mi][nj][2] + bb[nj].z;
                o.w = acc[mi][nj][3] + bb[nj].w;
                if (n + 3 < V_) {
                    *(float4*)(out + (size_t)b * V_ + n) = o;
                } else {
                    if (n + 0 < V_) out[(size_t)b * V_ + n + 0] = o.x;
                    if (n + 1 < V_) out[(size_t)b * V_ + n + 1] = o.y;
                    if (n + 2 < V_) out[(size_t)b * V_ + n + 2] = o.z;
                    if (n + 3 < V_) out[(size_t)b * V_ + n + 3] = o.w;
                }
            }
        }
    }
}

extern "C" void kernel_launch(void* const* d_in, const int* in_sizes, int n_in,
                              void* d_out, int out_size, void* d_ws, size_t ws_size,
                              hipStream_t stream) {
    const int* ids      = (const int*)d_in[0];
    const int* msk      = (const int*)d_in[1];
    const float* emb    = (const float*)d_in[2];
    const float* attn_a = (const float*)d_in[3];
    const float* attn_b = (const float*)d_in[4];
    const float* rbias  = (const float*)d_in[5];
    float* out = (float*)d_out;

    unsigned short* aT      = (unsigned short*)d_ws;                     // 32 KB
    unsigned short* user_bf = (unsigned short*)((char*)d_ws + 32768);    // 512 KB
    unsigned short* emb_bf  = (unsigned short*)((char*)d_ws + 32768 + 524288);  // 12.8 MB
    int use_bf = (ws_size >= (size_t)(32768 + 524288 + 12800000)) ? 1 : 0;

    // DIAGNOSTIC ROUND: duplicated idempotent dispatches to decompose per-kernel
    // time from the total. T4 = T2 + 2*t_user + t_logits (T2 = 211.3us).
    k_prep<<<64, 256, 0, stream>>>(attn_a, aT);
    if (use_bf) k_convE<<<3125, 256, 0, stream>>>(emb, emb_bf);
    k_user<<<2048, 256, 0, stream>>>(ids, msk, emb, emb_bf, aT, attn_b, user_bf, use_bf);
    k_user<<<2048, 256, 0, stream>>>(ids, msk, emb, emb_bf, aT, attn_b, user_bf, use_bf);
    k_user<<<2048, 256, 0, stream>>>(ids, msk, emb, emb_bf, aT, attn_b, user_bf, use_bf);
    k_logits<<<dim3(2, (V_ + 127) / 128), 256, 0, stream>>>(user_bf, emb, emb_bf, rbias, out, use_bf);
    k_logits<<<dim3(2, (V_ + 127) / 128), 256, 0, stream>>>(user_bf, emb, emb_bf, rbias, out, use_bf);
}

// Round 5
// 234.302 us; speedup vs baseline: 1.9780x; 1.9780x over previous
//
#include <hip/hip_runtime.h>
#include <hip/hip_bf16.h>
#include <stdint.h>

#define B_ 2048
#define L_ 128
#define V_ 50000
#define D_ 128

typedef __attribute__((ext_vector_type(8))) short bf16x8;
typedef __attribute__((ext_vector_type(8))) unsigned short ushort8;
typedef __attribute__((ext_vector_type(4))) float f32x4;

__device__ inline unsigned short f2bf(float f) {
    union { float f; uint32_t u; } v; v.f = f;
    uint32_t u = v.u + 0x7FFFu + ((v.u >> 16) & 1u);   // RNE
    return (unsigned short)(u >> 16);
}
__device__ inline float bf2f(unsigned short h) {
    union { uint32_t u; float f; } v; v.u = ((uint32_t)h) << 16;
    return v.f;
}
__device__ inline float tanh_fast(float x) {
    float xc = fminf(fmaxf(x, -15.f), 15.f);
    float z = __expf(2.f * xc);
    return (z - 1.f) / (z + 1.f);
}
// load 8 fp32 -> bf16x8 (fallback path only)
__device__ inline bf16x8 ld8f(const float* p) {
    float4 x0 = *(const float4*)p;
    float4 x1 = *(const float4*)(p + 4);
    ushort8 v;
    v[0] = f2bf(x0.x); v[1] = f2bf(x0.y); v[2] = f2bf(x0.z); v[3] = f2bf(x0.w);
    v[4] = f2bf(x1.x); v[5] = f2bf(x1.y); v[6] = f2bf(x1.z); v[7] = f2bf(x1.w);
    union { ushort8 u; bf16x8 b; } c; c.u = v; return c.b;
}

// ---------------- kernel 0: aT_bf16[n][d] = bf16(attn_a[d][n]) ----------------
__global__ __launch_bounds__(256) void k_prep(const float* __restrict__ a,
                                              unsigned short* __restrict__ aT) {
    int i = blockIdx.x * 256 + threadIdx.x;   // 16384 elems
    int d = i >> 7, n = i & 127;
    aT[n * 128 + d] = f2bf(a[d * 128 + n]);
}

// ---------------- kernel 0b: emb_bf[v][d] = bf16(emb[v][d]) ----------------
__global__ __launch_bounds__(256) void k_convE(const float* __restrict__ emb,
                                               unsigned short* __restrict__ emb_bf) {
    size_t i = ((size_t)blockIdx.x * 256 + threadIdx.x) * 8;  // 6,400,000 elems, grid exact
    float4 x0 = *(const float4*)(emb + i);
    float4 x1 = *(const float4*)(emb + i + 4);
    ushort8 v;
    v[0] = f2bf(x0.x); v[1] = f2bf(x0.y); v[2] = f2bf(x0.z); v[3] = f2bf(x0.w);
    v[4] = f2bf(x1.x); v[5] = f2bf(x1.y); v[6] = f2bf(x1.z); v[7] = f2bf(x1.w);
    *(ushort8*)(emb_bf + i) = v;
}

// ---------------- kernel 1: user_bf16[b][d]  (unchanged from round 2) ----------------
__global__ __launch_bounds__(256) void k_user(
    const int* __restrict__ ids, const int* __restrict__ msk,
    const float* __restrict__ emb, const unsigned short* __restrict__ emb_bf,
    const unsigned short* __restrict__ aT,
    const float* __restrict__ bvec, unsigned short* __restrict__ user_bf,
    int use_bf) {
    __shared__ __align__(16) unsigned short lh[128 * 128];  // h tile, swizzled (32KB)
    __shared__ float l_e[128];
    __shared__ float l_attn[128];
    __shared__ float l_p[256];

    int b = blockIdx.x;
    int t = threadIdx.x;

    {
        int row = t >> 1, half = t & 1;
        int id = ids[b * L_ + row];
        if (use_bf) {
            const unsigned short* src = emb_bf + (size_t)id * D_ + half * 64;
#pragma unroll
            for (int q = 0; q < 8; ++q) {
                ushort8 v = *(const ushort8*)(src + q * 8);
                int c = half * 64 + q * 8;
                *(ushort8*)&lh[row * 128 + (c ^ ((row & 7) << 3))] = v;
            }
        } else {
            const float* src = emb + (size_t)id * D_ + half * 64;
#pragma unroll
            for (int q = 0; q < 8; ++q) {
                float4 x0 = *(const float4*)(src + q * 8);
                float4 x1 = *(const float4*)(src + q * 8 + 4);
                ushort8 v;
                v[0] = f2bf(x0.x); v[1] = f2bf(x0.y); v[2] = f2bf(x0.z); v[3] = f2bf(x0.w);
                v[4] = f2bf(x1.x); v[5] = f2bf(x1.y); v[6] = f2bf(x1.z); v[7] = f2bf(x1.w);
                int c = half * 64 + q * 8;
                *(ushort8*)&lh[row * 128 + (c ^ ((row & 7) << 3))] = v;
            }
        }
    }
    __syncthreads();

    int wave = t >> 6, lane = t & 63, lo = lane & 15, hi = lane >> 4;

    f32x4 acc[2][8] = {};
#pragma unroll
    for (int kk = 0; kk < 4; ++kk) {
        int kc = kk * 32 + hi * 8;
        bf16x8 afr[2];
#pragma unroll
        for (int mi = 0; mi < 2; ++mi) {
            int row = wave * 32 + mi * 16 + lo;
            afr[mi] = *(const bf16x8*)&lh[row * 128 + (kc ^ ((row & 7) << 3))];
        }
#pragma unroll
        for (int nj = 0; nj < 8; ++nj) {
            int col = nj * 16 + lo;
            bf16x8 bfr = *(const bf16x8*)(aT + col * 128 + kc);
            acc[0][nj] = __builtin_amdgcn_mfma_f32_16x16x32_bf16(afr[0], bfr, acc[0][nj], 0, 0, 0);
            acc[1][nj] = __builtin_amdgcn_mfma_f32_16x16x32_bf16(afr[1], bfr, acc[1][nj], 0, 0, 0);
        }
    }

    float bv[8];
#pragma unroll
    for (int nj = 0; nj < 8; ++nj) bv[nj] = bvec[nj * 16 + lo];
#pragma unroll
    for (int mi = 0; mi < 2; ++mi) {
#pragma unroll
        for (int reg = 0; reg < 4; ++reg) {
            float p = 0.f;
#pragma unroll
            for (int nj = 0; nj < 8; ++nj) p += tanh_fast(acc[mi][nj][reg]) * bv[nj];
            p += __shfl_xor(p, 1); p += __shfl_xor(p, 2);
            p += __shfl_xor(p, 4); p += __shfl_xor(p, 8);
            int row = wave * 32 + mi * 16 + hi * 4 + reg;
            if (lo == 0) l_e[row] = p;
        }
    }
    __syncthreads();

    if (t < 128) {
        float e = l_e[t];
        float at = 0.f;
        if (msk[b * L_ + t]) at = 1.f / (1.f + __expf(-e));
        l_attn[t] = at;
    }
    __syncthreads();

    {
        int d = t & 127, half = t >> 7;
        float s = 0.f;
#pragma unroll 8
        for (int l = half * 64; l < half * 64 + 64; ++l)
            s += l_attn[l] * bf2f(lh[l * 128 + (d ^ ((l & 7) << 3))]);
        l_p[t] = s;
    }
    __syncthreads();
    if (t < 128) {
        float u = l_p[t] + l_p[t + 128];
        user_bf[b * 128 + t] = f2bf(u);
    }
}

// ---------------- kernel 2: logits = user_bf16 @ emb^T + bias ----------------
// NEW: LDS-free, write-locality-tiled. Grid (32 m-chunks, 49 n-chunks).
// Block tile: 64m x 1024n processed as 4 phases of 256n. All 4 waves cover the
// same 64 rows; wave w owns cols [phase*256 + w*64, +64). Per phase each output
// row receives 1KB contiguous (4 waves x 256B adjacent), 4KB per block-row
// within a few us -> HBM writeback page clustering (vs 512B random before).
// emb/user fragments read directly from global (L2/L3-resident).
__global__ __launch_bounds__(256) void k_logits(
    const unsigned short* __restrict__ user_bf, const float* __restrict__ emb,
    const unsigned short* __restrict__ emb_bf,
    const float* __restrict__ bias, float* __restrict__ out, int use_bf) {
    int t = threadIdx.x;
    int wave = t >> 6, lane = t & 63, lo = lane & 15, hi = lane >> 4;
    int m0 = blockIdx.x * 64;       // 32 chunks x 64 rows
    int nbase = blockIdx.y * 1024;  // 49 chunks x 1024 cols (49*1024 = 50176 >= V_)

    // user (B-operand) fragments: rows b = m0 + mi*16 + lo, loaded once
    bf16x8 ufr[4][4];
#pragma unroll
    for (int mi = 0; mi < 4; ++mi) {
        const unsigned short* up = user_bf + (size_t)(m0 + mi * 16 + lo) * 128 + hi * 8;
#pragma unroll
        for (int kk = 0; kk < 4; ++kk)
            ufr[mi][kk] = *(const bf16x8*)(up + kk * 32);
    }

#pragma unroll 1
    for (int ph = 0; ph < 4; ++ph) {
        int n_w = nbase + ph * 256 + wave * 64;   // this wave's 64-col group

        f32x4 acc[4][4] = {};   // [mi][nj]
#pragma unroll
        for (int kk = 0; kk < 4; ++kk) {
            int kc = kk * 32 + hi * 8;
            bf16x8 efr[4];
#pragma unroll
            for (int nj = 0; nj < 4; ++nj) {
                int col = n_w + nj * 16 + lo;
                int cc = (col < V_) ? col : 0;    // row 0 of emb is zeros anyway
                if (use_bf) {
                    efr[nj] = *(const bf16x8*)(emb_bf + (size_t)cc * 128 + kc);
                } else {
                    efr[nj] = ld8f(emb + (size_t)cc * 128 + kc);
                }
            }
#pragma unroll
            for (int nj = 0; nj < 4; ++nj)
#pragma unroll
                for (int mi = 0; mi < 4; ++mi)
                    // swapped: D[col=lo -> b][row=hi*4+reg -> n]
                    acc[mi][nj] = __builtin_amdgcn_mfma_f32_16x16x32_bf16(
                        efr[nj], ufr[mi][kk], acc[mi][nj], 0, 0, 0);
        }

        // bias for this phase: n = n_w + nj*16 + hi*4 + reg
        float4 bb[4];
#pragma unroll
        for (int nj = 0; nj < 4; ++nj) {
            int n = n_w + nj * 16 + hi * 4;
            if (n + 3 < V_) {
                bb[nj] = *(const float4*)(bias + n);
            } else {
                bb[nj].x = (n + 0 < V_) ? bias[n + 0] : 0.f;
                bb[nj].y = (n + 1 < V_) ? bias[n + 1] : 0.f;
                bb[nj].z = (n + 2 < V_) ? bias[n + 2] : 0.f;
                bb[nj].w = (n + 3 < V_) ? bias[n + 3] : 0.f;
            }
        }

        // stores: per (mi,nj) instr = 16 rows x 64B; per row per phase = 1KB
#pragma unroll
        for (int mi = 0; mi < 4; ++mi) {
            int b = m0 + mi * 16 + lo;
#pragma unroll
            for (int nj = 0; nj < 4; ++nj) {
                int n = n_w + nj * 16 + hi * 4;
                float4 o;
                o.x = acc[mi][nj][0] + bb[nj].x;
                o.y = acc[mi][nj][1] + bb[nj].y;
                o.z = acc[mi][nj][2] + bb[nj].z;
                o.w = acc[mi][nj][3] + bb[nj].w;
                if (n + 3 < V_) {
                    *(float4*)(out + (size_t)b * V_ + n) = o;
                } else {
                    if (n + 0 < V_) out[(size_t)b * V_ + n + 0] = o.x;
                    if (n + 1 < V_) out[(size_t)b * V_ + n + 1] = o.y;
                    if (n + 2 < V_) out[(size_t)b * V_ + n + 2] = o.z;
                    if (n + 3 < V_) out[(size_t)b * V_ + n + 3] = o.w;
                }
            }
        }
    }
}

extern "C" void kernel_launch(void* const* d_in, const int* in_sizes, int n_in,
                              void* d_out, int out_size, void* d_ws, size_t ws_size,
                              hipStream_t stream) {
    const int* ids      = (const int*)d_in[0];
    const int* msk      = (const int*)d_in[1];
    const float* emb    = (const float*)d_in[2];
    const float* attn_a = (const float*)d_in[3];
    const float* attn_b = (const float*)d_in[4];
    const float* rbias  = (const float*)d_in[5];
    float* out = (float*)d_out;

    unsigned short* aT      = (unsigned short*)d_ws;                     // 32 KB
    unsigned short* user_bf = (unsigned short*)((char*)d_ws + 32768);    // 512 KB
    unsigned short* emb_bf  = (unsigned short*)((char*)d_ws + 32768 + 524288);  // 12.8 MB
    int use_bf = (ws_size >= (size_t)(32768 + 524288 + 12800000)) ? 1 : 0;

    k_prep<<<64, 256, 0, stream>>>(attn_a, aT);
    if (use_bf) k_convE<<<3125, 256, 0, stream>>>(emb, emb_bf);
    k_user<<<2048, 256, 0, stream>>>(ids, msk, emb, emb_bf, aT, attn_b, user_bf, use_bf);
    k_logits<<<dim3(32, 49), 256, 0, stream>>>(user_bf, emb, emb_bf, rbias, out, use_bf);
}

// Round 6
// 209.865 us; speedup vs baseline: 2.2084x; 1.1164x over previous
//
#include <hip/hip_runtime.h>
#include <hip/hip_bf16.h>
#include <stdint.h>

#define B_ 2048
#define L_ 128
#define V_ 50000
#define D_ 128

typedef __attribute__((ext_vector_type(8))) short bf16x8;
typedef __attribute__((ext_vector_type(8))) unsigned short ushort8;
typedef __attribute__((ext_vector_type(4))) float f32x4;

__device__ inline unsigned short f2bf(float f) {
    union { float f; uint32_t u; } v; v.f = f;
    uint32_t u = v.u + 0x7FFFu + ((v.u >> 16) & 1u);   // RNE
    return (unsigned short)(u >> 16);
}
__device__ inline float bf2f(unsigned short h) {
    union { uint32_t u; float f; } v; v.u = ((uint32_t)h) << 16;
    return v.f;
}
__device__ inline float tanh_fast(float x) {
    float xc = fminf(fmaxf(x, -15.f), 15.f);
    float z = __expf(2.f * xc);
    return (z - 1.f) / (z + 1.f);
}
// load 8 fp32 -> bf16x8 (fallback path only)
__device__ inline bf16x8 ld8f(const float* p) {
    float4 x0 = *(const float4*)p;
    float4 x1 = *(const float4*)(p + 4);
    ushort8 v;
    v[0] = f2bf(x0.x); v[1] = f2bf(x0.y); v[2] = f2bf(x0.z); v[3] = f2bf(x0.w);
    v[4] = f2bf(x1.x); v[5] = f2bf(x1.y); v[6] = f2bf(x1.z); v[7] = f2bf(x1.w);
    union { ushort8 u; bf16x8 b; } c; c.u = v; return c.b;
}

// ---------------- kernel 0: aT_bf16[n][d] = bf16(attn_a[d][n]) ----------------
__global__ __launch_bounds__(256) void k_prep(const float* __restrict__ a,
                                              unsigned short* __restrict__ aT) {
    int i = blockIdx.x * 256 + threadIdx.x;   // 16384 elems
    int d = i >> 7, n = i & 127;
    aT[n * 128 + d] = f2bf(a[d * 128 + n]);
}

// ---------------- kernel 0b: emb_bf[v][d] = bf16(emb[v][d]) ----------------
__global__ __launch_bounds__(256) void k_convE(const float* __restrict__ emb,
                                               unsigned short* __restrict__ emb_bf) {
    size_t i = ((size_t)blockIdx.x * 256 + threadIdx.x) * 8;  // 6,400,000 elems, grid exact
    float4 x0 = *(const float4*)(emb + i);
    float4 x1 = *(const float4*)(emb + i + 4);
    ushort8 v;
    v[0] = f2bf(x0.x); v[1] = f2bf(x0.y); v[2] = f2bf(x0.z); v[3] = f2bf(x0.w);
    v[4] = f2bf(x1.x); v[5] = f2bf(x1.y); v[6] = f2bf(x1.z); v[7] = f2bf(x1.w);
    *(ushort8*)(emb_bf + i) = v;
}

// ---------------- kernel 1: user_bf16[b][d]  (unchanged from round 2) ----------------
__global__ __launch_bounds__(256) void k_user(
    const int* __restrict__ ids, const int* __restrict__ msk,
    const float* __restrict__ emb, const unsigned short* __restrict__ emb_bf,
    const unsigned short* __restrict__ aT,
    const float* __restrict__ bvec, unsigned short* __restrict__ user_bf,
    int use_bf) {
    __shared__ __align__(16) unsigned short lh[128 * 128];  // h tile, swizzled (32KB)
    __shared__ float l_e[128];
    __shared__ float l_attn[128];
    __shared__ float l_p[256];

    int b = blockIdx.x;
    int t = threadIdx.x;

    {
        int row = t >> 1, half = t & 1;
        int id = ids[b * L_ + row];
        if (use_bf) {
            const unsigned short* src = emb_bf + (size_t)id * D_ + half * 64;
#pragma unroll
            for (int q = 0; q < 8; ++q) {
                ushort8 v = *(const ushort8*)(src + q * 8);
                int c = half * 64 + q * 8;
                *(ushort8*)&lh[row * 128 + (c ^ ((row & 7) << 3))] = v;
            }
        } else {
            const float* src = emb + (size_t)id * D_ + half * 64;
#pragma unroll
            for (int q = 0; q < 8; ++q) {
                float4 x0 = *(const float4*)(src + q * 8);
                float4 x1 = *(const float4*)(src + q * 8 + 4);
                ushort8 v;
                v[0] = f2bf(x0.x); v[1] = f2bf(x0.y); v[2] = f2bf(x0.z); v[3] = f2bf(x0.w);
                v[4] = f2bf(x1.x); v[5] = f2bf(x1.y); v[6] = f2bf(x1.z); v[7] = f2bf(x1.w);
                int c = half * 64 + q * 8;
                *(ushort8*)&lh[row * 128 + (c ^ ((row & 7) << 3))] = v;
            }
        }
    }
    __syncthreads();

    int wave = t >> 6, lane = t & 63, lo = lane & 15, hi = lane >> 4;

    f32x4 acc[2][8] = {};
#pragma unroll
    for (int kk = 0; kk < 4; ++kk) {
        int kc = kk * 32 + hi * 8;
        bf16x8 afr[2];
#pragma unroll
        for (int mi = 0; mi < 2; ++mi) {
            int row = wave * 32 + mi * 16 + lo;
            afr[mi] = *(const bf16x8*)&lh[row * 128 + (kc ^ ((row & 7) << 3))];
        }
#pragma unroll
        for (int nj = 0; nj < 8; ++nj) {
            int col = nj * 16 + lo;
            bf16x8 bfr = *(const bf16x8*)(aT + col * 128 + kc);
            acc[0][nj] = __builtin_amdgcn_mfma_f32_16x16x32_bf16(afr[0], bfr, acc[0][nj], 0, 0, 0);
            acc[1][nj] = __builtin_amdgcn_mfma_f32_16x16x32_bf16(afr[1], bfr, acc[1][nj], 0, 0, 0);
        }
    }

    float bv[8];
#pragma unroll
    for (int nj = 0; nj < 8; ++nj) bv[nj] = bvec[nj * 16 + lo];
#pragma unroll
    for (int mi = 0; mi < 2; ++mi) {
#pragma unroll
        for (int reg = 0; reg < 4; ++reg) {
            float p = 0.f;
#pragma unroll
            for (int nj = 0; nj < 8; ++nj) p += tanh_fast(acc[mi][nj][reg]) * bv[nj];
            p += __shfl_xor(p, 1); p += __shfl_xor(p, 2);
            p += __shfl_xor(p, 4); p += __shfl_xor(p, 8);
            int row = wave * 32 + mi * 16 + hi * 4 + reg;
            if (lo == 0) l_e[row] = p;
        }
    }
    __syncthreads();

    if (t < 128) {
        float e = l_e[t];
        float at = 0.f;
        if (msk[b * L_ + t]) at = 1.f / (1.f + __expf(-e));
        l_attn[t] = at;
    }
    __syncthreads();

    {
        int d = t & 127, half = t >> 7;
        float s = 0.f;
#pragma unroll 8
        for (int l = half * 64; l < half * 64 + 64; ++l)
            s += l_attn[l] * bf2f(lh[l * 128 + (d ^ ((l & 7) << 3))]);
        l_p[t] = s;
    }
    __syncthreads();
    if (t < 128) {
        float u = l_p[t] + l_p[t + 128];
        user_bf[b * 128 + t] = f2bf(u);
    }
}

// ---------------- kernel 2: logits = user_bf16 @ emb^T + bias ----------------
// Grid 782 blocks; block owns 64 vocab cols for ALL 2048 rows -> emb read ONCE
// (12.8MB total). Each wave keeps its 64-col emb A-fragments in registers for
// the whole kernel, then independently (no LDS, no barriers) walks 16 row-chunks
// of 32 rows: 8 L2-hit user loads + 32 MFMA + 8 float4 stores per chunk.
// HBM traffic ~= 410MB writes + 13MB reads (user_bf re-reads are L2 hits).
__global__ __launch_bounds__(256) void k_logits(
    const unsigned short* __restrict__ user_bf, const float* __restrict__ emb,
    const unsigned short* __restrict__ emb_bf,
    const float* __restrict__ bias, float* __restrict__ out, int use_bf) {
    int t = threadIdx.x;
    int wave = t >> 6, lane = t & 63, lo = lane & 15, hi = lane >> 4;
    int n0 = blockIdx.x * 64;   // 782 blocks * 64 cols = 50048 >= V_

    // emb A-fragments for the block's 64 cols, resident all kernel (64 VGPR)
    // A-frag: lane holds M-row (=vocab col) = cg*16+lo, k = kk*32 + hi*8
    bf16x8 efr[4][4];
#pragma unroll
    for (int cg = 0; cg < 4; ++cg) {
        int col = n0 + cg * 16 + lo;
        int cc = (col < V_) ? col : 0;          // emb row 0 is all zeros
        const unsigned short* ep = emb_bf + (size_t)cc * 128 + hi * 8;
        if (use_bf) {
#pragma unroll
            for (int kk = 0; kk < 4; ++kk)
                efr[cg][kk] = *(const bf16x8*)(ep + kk * 32);
        } else {
            const float* ef = emb + (size_t)cc * 128 + hi * 8;
#pragma unroll
            for (int kk = 0; kk < 4; ++kk)
                efr[cg][kk] = ld8f(ef + kk * 32);
        }
    }

    // bias for this block's cols: n = n0 + cg*16 + hi*4 + reg
    float4 bb[4];
#pragma unroll
    for (int cg = 0; cg < 4; ++cg) {
        int n = n0 + cg * 16 + hi * 4;
        if (n + 3 < V_) {
            bb[cg] = *(const float4*)(bias + n);
        } else {
            bb[cg].x = (n + 0 < V_) ? bias[n + 0] : 0.f;
            bb[cg].y = (n + 1 < V_) ? bias[n + 1] : 0.f;
            bb[cg].z = (n + 2 < V_) ? bias[n + 2] : 0.f;
            bb[cg].w = (n + 3 < V_) ? bias[n + 3] : 0.f;
        }
    }

    // 64 row-chunks of 32; wave w takes chunks w, w+4, ... (independent waves)
#pragma unroll 1
    for (int c = wave; c < 64; c += 4) {
        int rbase = c * 32;

        // user B-fragments: B-frag lane holds N-col (=batch row) = mi*16+lo
        bf16x8 ufr[2][4];
#pragma unroll
        for (int mi = 0; mi < 2; ++mi) {
            const unsigned short* up = user_bf + (size_t)(rbase + mi * 16 + lo) * 128 + hi * 8;
#pragma unroll
            for (int kk = 0; kk < 4; ++kk)
                ufr[mi][kk] = *(const bf16x8*)(up + kk * 32);
        }

        f32x4 acc[4][2] = {};   // [cg][mi]
#pragma unroll
        for (int kk = 0; kk < 4; ++kk)
#pragma unroll
            for (int cg = 0; cg < 4; ++cg)
#pragma unroll
                for (int mi = 0; mi < 2; ++mi)
                    // D[row=hi*4+reg -> vocab col][col=lo -> batch row]
                    acc[cg][mi] = __builtin_amdgcn_mfma_f32_16x16x32_bf16(
                        efr[cg][kk], ufr[mi][kk], acc[cg][mi], 0, 0, 0);

        // stores: b = rbase + mi*16 + lo ; n = n0 + cg*16 + hi*4 (+reg)
#pragma unroll
        for (int mi = 0; mi < 2; ++mi) {
            int b = rbase + mi * 16 + lo;
#pragma unroll
            for (int cg = 0; cg < 4; ++cg) {
                int n = n0 + cg * 16 + hi * 4;
                float4 o;
                o.x = acc[cg][mi][0] + bb[cg].x;
                o.y = acc[cg][mi][1] + bb[cg].y;
                o.z = acc[cg][mi][2] + bb[cg].z;
                o.w = acc[cg][mi][3] + bb[cg].w;
                if (n + 3 < V_) {
                    *(float4*)(out + (size_t)b * V_ + n) = o;
                } else {
                    if (n + 0 < V_) out[(size_t)b * V_ + n + 0] = o.x;
                    if (n + 1 < V_) out[(size_t)b * V_ + n + 1] = o.y;
                    if (n + 2 < V_) out[(size_t)b * V_ + n + 2] = o.z;
                    if (n + 3 < V_) out[(size_t)b * V_ + n + 3] = o.w;
                }
            }
        }
    }
}

extern "C" void kernel_launch(void* const* d_in, const int* in_sizes, int n_in,
                              void* d_out, int out_size, void* d_ws, size_t ws_size,
                              hipStream_t stream) {
    const int* ids      = (const int*)d_in[0];
    const int* msk      = (const int*)d_in[1];
    const float* emb    = (const float*)d_in[2];
    const float* attn_a = (const float*)d_in[3];
    const float* attn_b = (const float*)d_in[4];
    const float* rbias  = (const float*)d_in[5];
    float* out = (float*)d_out;

    unsigned short* aT      = (unsigned short*)d_ws;                     // 32 KB
    unsigned short* user_bf = (unsigned short*)((char*)d_ws + 32768);    // 512 KB
    unsigned short* emb_bf  = (unsigned short*)((char*)d_ws + 32768 + 524288);  // 12.8 MB
    int use_bf = (ws_size >= (size_t)(32768 + 524288 + 12800000)) ? 1 : 0;

    k_prep<<<64, 256, 0, stream>>>(attn_a, aT);
    if (use_bf) k_convE<<<3125, 256, 0, stream>>>(emb, emb_bf);
    k_user<<<2048, 256, 0, stream>>>(ids, msk, emb, emb_bf, aT, attn_b, user_bf, use_bf);
    k_logits<<<782, 256, 0, stream>>>(user_bf, emb, emb_bf, rbias, out, use_bf);
}

// Round 7
// 205.110 us; speedup vs baseline: 2.2596x; 1.0232x over previous
//
#include <hip/hip_runtime.h>
#include <hip/hip_bf16.h>
#include <stdint.h>

#define B_ 2048
#define L_ 128
#define V_ 50000
#define D_ 128

typedef __attribute__((ext_vector_type(8))) short bf16x8;
typedef __attribute__((ext_vector_type(8))) unsigned short ushort8;
typedef __attribute__((ext_vector_type(4))) float f32x4;

__device__ inline unsigned short f2bf(float f) {
    union { float f; uint32_t u; } v; v.f = f;
    uint32_t u = v.u + 0x7FFFu + ((v.u >> 16) & 1u);   // RNE
    return (unsigned short)(u >> 16);
}
__device__ inline float bf2f(unsigned short h) {
    union { uint32_t u; float f; } v; v.u = ((uint32_t)h) << 16;
    return v.f;
}
__device__ inline float tanh_fast(float x) {
    float xc = fminf(fmaxf(x, -15.f), 15.f);
    float z = __expf(2.f * xc);
    return (z - 1.f) / (z + 1.f);
}
// load 8 fp32 -> bf16x8 (fallback path only)
__device__ inline bf16x8 ld8f(const float* p) {
    float4 x0 = *(const float4*)p;
    float4 x1 = *(const float4*)(p + 4);
    ushort8 v;
    v[0] = f2bf(x0.x); v[1] = f2bf(x0.y); v[2] = f2bf(x0.z); v[3] = f2bf(x0.w);
    v[4] = f2bf(x1.x); v[5] = f2bf(x1.y); v[6] = f2bf(x1.z); v[7] = f2bf(x1.w);
    union { ushort8 u; bf16x8 b; } c; c.u = v; return c.b;
}

// ---------------- kernel 0: aT_bf16[n][d] = bf16(attn_a[d][n]) ----------------
__global__ __launch_bounds__(256) void k_prep(const float* __restrict__ a,
                                              unsigned short* __restrict__ aT) {
    int i = blockIdx.x * 256 + threadIdx.x;   // 16384 elems
    int d = i >> 7, n = i & 127;
    aT[n * 128 + d] = f2bf(a[d * 128 + n]);
}

// ---------------- kernel 0b: emb_bf[v][d] = bf16(emb[v][d]) ----------------
__global__ __launch_bounds__(256) void k_convE(const float* __restrict__ emb,
                                               unsigned short* __restrict__ emb_bf) {
    size_t i = ((size_t)blockIdx.x * 256 + threadIdx.x) * 8;  // 6,400,000 elems, grid exact
    float4 x0 = *(const float4*)(emb + i);
    float4 x1 = *(const float4*)(emb + i + 4);
    ushort8 v;
    v[0] = f2bf(x0.x); v[1] = f2bf(x0.y); v[2] = f2bf(x0.z); v[3] = f2bf(x0.w);
    v[4] = f2bf(x1.x); v[5] = f2bf(x1.y); v[6] = f2bf(x1.z); v[7] = f2bf(x1.w);
    *(ushort8*)(emb_bf + i) = v;
}

// ---------------- kernel 1: user_bf16[b][d]  (unchanged) ----------------
__global__ __launch_bounds__(256) void k_user(
    const int* __restrict__ ids, const int* __restrict__ msk,
    const float* __restrict__ emb, const unsigned short* __restrict__ emb_bf,
    const unsigned short* __restrict__ aT,
    const float* __restrict__ bvec, unsigned short* __restrict__ user_bf,
    int use_bf) {
    __shared__ __align__(16) unsigned short lh[128 * 128];  // h tile, swizzled (32KB)
    __shared__ float l_e[128];
    __shared__ float l_attn[128];
    __shared__ float l_p[256];

    int b = blockIdx.x;
    int t = threadIdx.x;

    {
        int row = t >> 1, half = t & 1;
        int id = ids[b * L_ + row];
        if (use_bf) {
            const unsigned short* src = emb_bf + (size_t)id * D_ + half * 64;
#pragma unroll
            for (int q = 0; q < 8; ++q) {
                ushort8 v = *(const ushort8*)(src + q * 8);
                int c = half * 64 + q * 8;
                *(ushort8*)&lh[row * 128 + (c ^ ((row & 7) << 3))] = v;
            }
        } else {
            const float* src = emb + (size_t)id * D_ + half * 64;
#pragma unroll
            for (int q = 0; q < 8; ++q) {
                float4 x0 = *(const float4*)(src + q * 8);
                float4 x1 = *(const float4*)(src + q * 8 + 4);
                ushort8 v;
                v[0] = f2bf(x0.x); v[1] = f2bf(x0.y); v[2] = f2bf(x0.z); v[3] = f2bf(x0.w);
                v[4] = f2bf(x1.x); v[5] = f2bf(x1.y); v[6] = f2bf(x1.z); v[7] = f2bf(x1.w);
                int c = half * 64 + q * 8;
                *(ushort8*)&lh[row * 128 + (c ^ ((row & 7) << 3))] = v;
            }
        }
    }
    __syncthreads();

    int wave = t >> 6, lane = t & 63, lo = lane & 15, hi = lane >> 4;

    f32x4 acc[2][8] = {};
#pragma unroll
    for (int kk = 0; kk < 4; ++kk) {
        int kc = kk * 32 + hi * 8;
        bf16x8 afr[2];
#pragma unroll
        for (int mi = 0; mi < 2; ++mi) {
            int row = wave * 32 + mi * 16 + lo;
            afr[mi] = *(const bf16x8*)&lh[row * 128 + (kc ^ ((row & 7) << 3))];
        }
#pragma unroll
        for (int nj = 0; nj < 8; ++nj) {
            int col = nj * 16 + lo;
            bf16x8 bfr = *(const bf16x8*)(aT + col * 128 + kc);
            acc[0][nj] = __builtin_amdgcn_mfma_f32_16x16x32_bf16(afr[0], bfr, acc[0][nj], 0, 0, 0);
            acc[1][nj] = __builtin_amdgcn_mfma_f32_16x16x32_bf16(afr[1], bfr, acc[1][nj], 0, 0, 0);
        }
    }

    float bv[8];
#pragma unroll
    for (int nj = 0; nj < 8; ++nj) bv[nj] = bvec[nj * 16 + lo];
#pragma unroll
    for (int mi = 0; mi < 2; ++mi) {
#pragma unroll
        for (int reg = 0; reg < 4; ++reg) {
            float p = 0.f;
#pragma unroll
            for (int nj = 0; nj < 8; ++nj) p += tanh_fast(acc[mi][nj][reg]) * bv[nj];
            p += __shfl_xor(p, 1); p += __shfl_xor(p, 2);
            p += __shfl_xor(p, 4); p += __shfl_xor(p, 8);
            int row = wave * 32 + mi * 16 + hi * 4 + reg;
            if (lo == 0) l_e[row] = p;
        }
    }
    __syncthreads();

    if (t < 128) {
        float e = l_e[t];
        float at = 0.f;
        if (msk[b * L_ + t]) at = 1.f / (1.f + __expf(-e));
        l_attn[t] = at;
    }
    __syncthreads();

    {
        int d = t & 127, half = t >> 7;
        float s = 0.f;
#pragma unroll 8
        for (int l = half * 64; l < half * 64 + 64; ++l)
            s += l_attn[l] * bf2f(lh[l * 128 + (d ^ ((l & 7) << 3))]);
        l_p[t] = s;
    }
    __syncthreads();
    if (t < 128) {
        float u = l_p[t] + l_p[t + 128];
        user_bf[b * 128 + t] = f2bf(u);
    }
}

// ---------------- kernel 2: logits = user_bf16 @ emb^T + bias ----------------
// R6 macro-structure (782 blocks x 64 cols, emb read once, no barriers) + NEW
// per-wave LDS transpose epilogue: acc+bias -> 8KB/wave LDS tile, then dense
// read-back so each store instruction writes 4 rows x 256B (full 128B lines,
// consecutive lanes -> consecutive addresses) instead of 16 scattered 64B
// segments. Tests the per-instruction store-scatter hypothesis.
__global__ __launch_bounds__(256) void k_logits(
    const unsigned short* __restrict__ user_bf, const float* __restrict__ emb,
    const unsigned short* __restrict__ emb_bf,
    const float* __restrict__ bias, float* __restrict__ out, int use_bf) {
    __shared__ __align__(16) float lt[4][32 * 64];   // per-wave C-tile (32KB total)

    int t = threadIdx.x;
    int wave = t >> 6, lane = t & 63, lo = lane & 15, hi = lane >> 4;
    int n0 = blockIdx.x * 64;   // 782 blocks * 64 cols = 50048 >= V_

    // emb A-fragments for the block's 64 cols, resident all kernel (64 VGPR)
    bf16x8 efr[4][4];
#pragma unroll
    for (int cg = 0; cg < 4; ++cg) {
        int col = n0 + cg * 16 + lo;
        int cc = (col < V_) ? col : 0;          // emb row 0 is all zeros
        const unsigned short* ep = emb_bf + (size_t)cc * 128 + hi * 8;
        if (use_bf) {
#pragma unroll
            for (int kk = 0; kk < 4; ++kk)
                efr[cg][kk] = *(const bf16x8*)(ep + kk * 32);
        } else {
            const float* ef = emb + (size_t)cc * 128 + hi * 8;
#pragma unroll
            for (int kk = 0; kk < 4; ++kk)
                efr[cg][kk] = ld8f(ef + kk * 32);
        }
    }

    // bias: n = n0 + cg*16 + hi*4 + reg
    float4 bb[4];
#pragma unroll
    for (int cg = 0; cg < 4; ++cg) {
        int n = n0 + cg * 16 + hi * 4;
        if (n + 3 < V_) {
            bb[cg] = *(const float4*)(bias + n);
        } else {
            bb[cg].x = (n + 0 < V_) ? bias[n + 0] : 0.f;
            bb[cg].y = (n + 1 < V_) ? bias[n + 1] : 0.f;
            bb[cg].z = (n + 2 < V_) ? bias[n + 2] : 0.f;
            bb[cg].w = (n + 3 < V_) ? bias[n + 3] : 0.f;
        }
    }

    float* myt = lt[wave];

    // 64 row-chunks of 32; wave w takes chunks w, w+4, ... (independent waves)
#pragma unroll 1
    for (int c = wave; c < 64; c += 4) {
        int rbase = c * 32;

        // user B-fragments (L2-resident)
        bf16x8 ufr[2][4];
#pragma unroll
        for (int mi = 0; mi < 2; ++mi) {
            const unsigned short* up = user_bf + (size_t)(rbase + mi * 16 + lo) * 128 + hi * 8;
#pragma unroll
            for (int kk = 0; kk < 4; ++kk)
                ufr[mi][kk] = *(const bf16x8*)(up + kk * 32);
        }

        f32x4 acc[4][2] = {};   // [cg][mi]
#pragma unroll
        for (int kk = 0; kk < 4; ++kk)
#pragma unroll
            for (int cg = 0; cg < 4; ++cg)
#pragma unroll
                for (int mi = 0; mi < 2; ++mi)
                    // D[row=hi*4+reg -> vocab col][col=lo -> batch row]
                    acc[cg][mi] = __builtin_amdgcn_mfma_f32_16x16x32_bf16(
                        efr[cg][kk], ufr[mi][kk], acc[cg][mi], 0, 0, 0);

        // ---- epilogue A: acc+bias -> LDS tile [b_loc][n_loc], chunk-XOR swizzle
#pragma unroll
        for (int mi = 0; mi < 2; ++mi) {
            int b_loc = mi * 16 + lo;
#pragma unroll
            for (int cg = 0; cg < 4; ++cg) {
                f32x4 o;
                o[0] = acc[cg][mi][0] + bb[cg].x;
                o[1] = acc[cg][mi][1] + bb[cg].y;
                o[2] = acc[cg][mi][2] + bb[cg].z;
                o[3] = acc[cg][mi][3] + bb[cg].w;
                int ch = (cg * 4 + hi) ^ (b_loc & 15);
                *(f32x4*)&myt[b_loc * 64 + ch * 4] = o;
            }
        }
        // wave-synchronous: compiler inserts lgkmcnt wait before reads below

        // ---- epilogue B: dense read-back + store. Per instr: lanes 0..15 cover
        // one row's 256B (16 consecutive 16B chunks), hi selects row -> 4 rows
        // x 256B = full-line dense stores.
#pragma unroll
        for (int it = 0; it < 8; ++it) {
            int b_loc = it * 4 + hi;
            f32x4 v = *(const f32x4*)&myt[b_loc * 64 + ((lo ^ (b_loc & 15)) * 4)];
            int n = n0 + lo * 4;
            if (n + 3 < V_) {
                *(f32x4*)(out + (size_t)(rbase + b_loc) * V_ + n) = v;
            }
        }
    }
}

extern "C" void kernel_launch(void* const* d_in, const int* in_sizes, int n_in,
                              void* d_out, int out_size, void* d_ws, size_t ws_size,
                              hipStream_t stream) {
    const int* ids      = (const int*)d_in[0];
    const int* msk      = (const int*)d_in[1];
    const float* emb    = (const float*)d_in[2];
    const float* attn_a = (const float*)d_in[3];
    const float* attn_b = (const float*)d_in[4];
    const float* rbias  = (const float*)d_in[5];
    float* out = (float*)d_out;

    unsigned short* aT      = (unsigned short*)d_ws;                     // 32 KB
    unsigned short* user_bf = (unsigned short*)((char*)d_ws + 32768);    // 512 KB
    unsigned short* emb_bf  = (unsigned short*)((char*)d_ws + 32768 + 524288);  // 12.8 MB
    int use_bf = (ws_size >= (size_t)(32768 + 524288 + 12800000)) ? 1 : 0;

    k_prep<<<64, 256, 0, stream>>>(attn_a, aT);
    if (use_bf) k_convE<<<3125, 256, 0, stream>>>(emb, emb_bf);
    k_user<<<2048, 256, 0, stream>>>(ids, msk, emb, emb_bf, aT, attn_b, user_bf, use_bf);
    k_logits<<<782, 256, 0, stream>>>(user_bf, emb, emb_bf, rbias, out, use_bf);
}